// Round 1
// baseline (595.504 us; speedup 1.0000x reference)
//
#include <hip/hip_runtime.h>

#define NB 65536
#define NTOT 704
#define NCLS 1000
#define NPAD 1024
#define KDIM 704
#define TWOPI 6.28318530717958647692f

typedef __attribute__((ext_vector_type(8))) short bf16x8;
typedef __attribute__((ext_vector_type(4))) float f32x4;

__device__ __forceinline__ float wsum_f(float v) {
#pragma unroll
  for (int o = 32; o > 0; o >>= 1) v += __shfl_xor(v, o, 64);
  return v;
}
__device__ __forceinline__ int wsum_i(int v) {
#pragma unroll
  for (int o = 32; o > 0; o >>= 1) v += __shfl_xor(v, o, 64);
  return v;
}
__device__ __forceinline__ float wmin_f(float v) {
#pragma unroll
  for (int o = 32; o > 0; o >>= 1) v = fminf(v, __shfl_xor(v, o, 64));
  return v;
}

__device__ __forceinline__ unsigned short f2bf(float v) {
  unsigned u = __float_as_uint(v);
  u = (u + 0x7FFFu + ((u >> 16) & 1u)) >> 16;   // RNE
  return (unsigned short)u;
}

// ---------------- W -> bf16 (padded to NPAD rows) ----------------
__global__ __launch_bounds__(256) void convw_kernel(const float* __restrict__ W,
                                                    unsigned short* __restrict__ Wb) {
  int i = blockIdx.x * 256 + threadIdx.x;
  if (i >= NPAD * KDIM) return;
  int n = i / KDIM;
  float v = (n < NCLS) ? W[i] : 0.0f;
  Wb[i] = f2bf(v);
}

// ---------------- oscillator sim + quantile gate -> rate(bf16) ----------------
__global__ __launch_bounds__(256) void sim_kernel(const float* __restrict__ x,
                                                  const float* __restrict__ p0,
                                                  unsigned short* __restrict__ rateb) {
  const int wave = threadIdx.x >> 6;
  const int lane = threadIdx.x & 63;
  const int sample = blockIdx.x * 4 + wave;
  const size_t base = (size_t)sample * NTOT;

  float phi[11], amp[11], freq[11];
#pragma unroll
  for (int e = 0; e < 11; ++e) {
    const int idx = e * 64 + lane;
    phi[e] = p0[base + idx] * TWOPI;
    amp[e] = 1.0f + fabsf(x[base + idx]) * 0.01f;
    float f;
    if (e == 0)      f = 1.0f + 3.0f * (float)idx / 63.0f;
    else if (e < 3)  f = 4.0f + 4.0f * (float)(idx - 64) / 127.0f;
    else             f = 30.0f + 50.0f * (float)(idx - 192) / 511.0f;
    freq[e] = f;
  }

#pragma unroll 1
  for (int s = 0; s < 5; ++s) {
    float sn[11], cn[11];
#pragma unroll
    for (int e = 0; e < 11; ++e) { sn[e] = __sinf(phi[e]); cn[e] = __cosf(phi[e]); }
    const float Sd = wsum_f(sn[0]);
    const float Cd = wsum_f(cn[0]);
    const float St = wsum_f(sn[1] + sn[2]);
    const float Ct = wsum_f(cn[1] + cn[2]);
    const float sg8 = ((sn[3] + sn[4]) + (sn[5] + sn[6])) + ((sn[7] + sn[8]) + (sn[9] + sn[10]));
    const float cg8 = ((cn[3] + cn[4]) + (cn[5] + cn[6])) + ((cn[7] + cn[8]) + (cn[9] + cn[10]));
    const float Sg = wsum_f(sg8);
    const float Cg = wsum_f(cg8);
    const float Sdm = Sd * (1.0f / 64.0f),  Cdm = Cd * (1.0f / 64.0f);
    const float Stm = St * (1.0f / 128.0f), Ctm = Ct * (1.0f / 128.0f);
    const float Sgm = Sg * (1.0f / 512.0f), Cgm = Cg * (1.0f / 512.0f);
    const float cpd = Cdm / sqrtf(Sdm * Sdm + Cdm * Cdm);   // cos(psi_delta)
    const float cpt = Ctm / sqrtf(Stm * Stm + Ctm * Ctm);   // cos(psi_theta)
#pragma unroll
    for (int e = 0; e < 11; ++e) {
      float Sm, Cm, pac;
      if (e == 0)     { Sm = Sdm; Cm = Cdm; pac = 0.0f; }
      else if (e < 3) { Sm = Stm; Cm = Ctm; pac = 0.3f * cpd; }
      else            { Sm = Sgm; Cm = Cgm; pac = 0.3f * cpt; }
      const float dphi = TWOPI * freq[e] + 2.0f * (Sm * cn[e] - Cm * sn[e]);
      phi[e] = fmodf(phi[e] + 0.01f * dphi, TWOPI);
      amp[e] = amp[e] + 0.01f * (pac * amp[e]);
    }
  }

  float raw[11];
  unsigned bits[11];
#pragma unroll
  for (int e = 0; e < 11; ++e) {
    raw[e] = amp[e] * 0.5f * (1.0f + __cosf(phi[e]));
    bits[e] = __float_as_uint(raw[e]);   // raw >= 0 -> bit order == value order
  }

  // 633rd smallest (0-indexed 632): minimal u with count(<= u) >= 633
  unsigned pre = 0;
#pragma unroll 1
  for (int bit = 31; bit >= 0; --bit) {
    const unsigned utry = pre | ((1u << bit) - 1u);
    int c = 0;
#pragma unroll
    for (int e = 0; e < 11; ++e) c += (bits[e] <= utry) ? 1 : 0;
    c = wsum_i(c);
    if (c < 633) pre |= (1u << bit);
  }
  const float S632 = __uint_as_float(pre);
  int cle = 0;
#pragma unroll
  for (int e = 0; e < 11; ++e) cle += (bits[e] <= pre) ? 1 : 0;
  cle = wsum_i(cle);
  float S633;
  if (cle >= 634) {
    S633 = S632;
  } else {
    float mn = 3.0e38f;
#pragma unroll
    for (int e = 0; e < 11; ++e) if (raw[e] > S632) mn = fminf(mn, raw[e]);
    S633 = wmin_f(mn);
  }
  const float q = 0.9f * 703.0f;                     // JAX: index = q*(n-1) in f32
  const float thr = S632 * (633.0f - q) + S633 * (q - 632.0f);

#pragma unroll
  for (int e = 0; e < 11; ++e) {
    const float r = raw[e];
    const float sg = 1.0f / (1.0f + __expf((thr - r) * 10.0f));
    rateb[base + e * 64 + lane] = f2bf(r * sg);
  }
}

// ---------------- bf16 MFMA GEMM: out = rate @ W^T + b ----------------
#define BM 128
#define BN 128
#define BK 64

__device__ __forceinline__ void gload16(const unsigned short* g, unsigned short* l) {
  __builtin_amdgcn_global_load_lds((const __attribute__((address_space(1))) void*)g,
                                   (__attribute__((address_space(3))) void*)l,
                                   16, 0, 0);
}

__global__ __launch_bounds__(256) void gemm_kernel(const unsigned short* __restrict__ A,
                                                   const unsigned short* __restrict__ Bw,
                                                   const float* __restrict__ bias,
                                                   float* __restrict__ C) {
  __shared__ unsigned short lA[BM * BK];
  __shared__ unsigned short lB[BN * BK];
  const int tid  = threadIdx.x;
  const int wave = tid >> 6;
  const int lane = tid & 63;

  // XCD-bijective swizzle (nwg=4096, 8 XCDs, 512 per XCD)
  const int bid = blockIdx.x;
  const int swz = (bid & 7) * 512 + (bid >> 3);
  const int bm = swz >> 3;     // 0..511
  const int bn = swz & 7;      // 0..7

  const int wr = wave >> 1;    // 0..1
  const int wc = wave & 1;     // 0..1

  f32x4 acc[4][4];
#pragma unroll
  for (int i = 0; i < 4; ++i)
#pragma unroll
    for (int j = 0; j < 4; ++j) acc[i][j] = (f32x4){0.f, 0.f, 0.f, 0.f};

  const int lrow = lane >> 3;         // 0..7 within 8-row chunk
  const int lk   = (lane & 7) * 8;    // k elem offset within BK

  for (int kt = 0; kt < KDIM / BK; ++kt) {
    const int k0 = kt * BK;
#pragma unroll
    for (int i = 0; i < 4; ++i) {
      const int c = wave * 4 + i;                    // chunk 0..15, wave-uniform
      const size_t garow = (size_t)(bm * BM + c * 8 + lrow);
      gload16(A + garow * KDIM + k0 + lk, lA + c * 512);
      const size_t gbrow = (size_t)(bn * BN + c * 8 + lrow);
      gload16(Bw + gbrow * KDIM + k0 + lk, lB + c * 512);
    }
    __syncthreads();
#pragma unroll
    for (int ks = 0; ks < 2; ++ks) {
      bf16x8 av[4], bv[4];
#pragma unroll
      for (int m = 0; m < 4; ++m)
        av[m] = *(const bf16x8*)&lA[(wr * 64 + m * 16 + (lane & 15)) * BK + ks * 32 + (lane >> 4) * 8];
#pragma unroll
      for (int n = 0; n < 4; ++n)
        bv[n] = *(const bf16x8*)&lB[(wc * 64 + n * 16 + (lane & 15)) * BK + ks * 32 + (lane >> 4) * 8];
#pragma unroll
      for (int m = 0; m < 4; ++m)
#pragma unroll
        for (int n = 0; n < 4; ++n)
          acc[m][n] = __builtin_amdgcn_mfma_f32_16x16x32_bf16(av[m], bv[n], acc[m][n], 0, 0, 0);
    }
    __syncthreads();
  }

  // epilogue: D[row = (lane>>4)*4 + r][col = lane&15] per 16x16 frag
  const int crow0 = bm * BM + wr * 64;
  const int ccol0 = bn * BN + wc * 64;
  const int rql = (lane >> 4) * 4;
  const int cl  = lane & 15;
#pragma unroll
  for (int n = 0; n < 4; ++n) {
    const int col = ccol0 + n * 16 + cl;
    if (col < NCLS) {
      const float bb = bias[col];
#pragma unroll
      for (int m = 0; m < 4; ++m) {
#pragma unroll
        for (int r = 0; r < 4; ++r) {
          const int row = crow0 + m * 16 + rql + r;
          C[(size_t)row * NCLS + col] = acc[m][n][r] + bb;
        }
      }
    }
  }
}

extern "C" void kernel_launch(void* const* d_in, const int* in_sizes, int n_in,
                              void* d_out, int out_size, void* d_ws, size_t ws_size,
                              hipStream_t stream) {
  const float* x    = (const float*)d_in[0];
  const float* p0   = (const float*)d_in[1];
  const float* W    = (const float*)d_in[2];
  const float* bias = (const float*)d_in[3];
  float* out = (float*)d_out;

  unsigned short* Wb    = (unsigned short*)d_ws;                       // NPAD*KDIM bf16
  unsigned short* rateb = (unsigned short*)d_ws + (size_t)NPAD * KDIM; // NB*NTOT bf16

  convw_kernel<<<dim3((NPAD * KDIM + 255) / 256), dim3(256), 0, stream>>>(W, Wb);
  sim_kernel<<<dim3(NB / 4), dim3(256), 0, stream>>>(x, p0, rateb);
  gemm_kernel<<<dim3((NB / BM) * (NPAD / BN)), dim3(256), 0, stream>>>(rateb, Wb, bias, out);
}

// Round 2
// 442.797 us; speedup vs baseline: 1.3449x; 1.3449x over previous
//
#include <hip/hip_runtime.h>

#define NB 65536
#define NTOT 704
#define NCLS 1000
#define NPAD 1024
#define KDIM 704
#define TWOPI 6.28318530717958647692f

typedef __attribute__((ext_vector_type(8))) short bf16x8;
typedef __attribute__((ext_vector_type(4))) float f32x4;

__device__ __forceinline__ float wsum_f(float v) {
#pragma unroll
  for (int o = 32; o > 0; o >>= 1) v += __shfl_xor(v, o, 64);
  return v;
}
__device__ __forceinline__ int wsum_i(int v) {
#pragma unroll
  for (int o = 32; o > 0; o >>= 1) v += __shfl_xor(v, o, 64);
  return v;
}
__device__ __forceinline__ float wmin_f(float v) {
#pragma unroll
  for (int o = 32; o > 0; o >>= 1) v = fminf(v, __shfl_xor(v, o, 64));
  return v;
}

__device__ __forceinline__ unsigned short f2bf(float v) {
  unsigned u = __float_as_uint(v);
  u = (u + 0x7FFFu + ((u >> 16) & 1u)) >> 16;   // RNE
  return (unsigned short)u;
}

// ---------------- W -> bf16 (padded to NPAD rows) ----------------
__global__ __launch_bounds__(256) void convw_kernel(const float* __restrict__ W,
                                                    unsigned short* __restrict__ Wb) {
  int i = blockIdx.x * 256 + threadIdx.x;
  if (i >= NPAD * KDIM) return;
  int n = i / KDIM;
  float v = (n < NCLS) ? W[i] : 0.0f;
  Wb[i] = f2bf(v);
}

// ---------------- oscillator sim + quantile gate -> rate(bf16) ----------------
__global__ __launch_bounds__(256) void sim_kernel(const float* __restrict__ x,
                                                  const float* __restrict__ p0,
                                                  unsigned short* __restrict__ rateb) {
  const int wave = threadIdx.x >> 6;
  const int lane = threadIdx.x & 63;
  const int sample = blockIdx.x * 4 + wave;
  const size_t base = (size_t)sample * NTOT;

  // state: s=sin(phi), c=cos(phi). Per-step const rotation (dc,ds) = (cos,sin)(2*pi*f*dt)
  float s[11], c[11], amp0[11], dc[11], ds[11];
#pragma unroll
  for (int e = 0; e < 11; ++e) {
    const int idx = e * 64 + lane;
    const float p = p0[base + idx];            // phase in revolutions [0,1)
    s[e] = __builtin_amdgcn_sinf(p);           // v_sin: sin(2*pi*p)
    c[e] = __builtin_amdgcn_cosf(p);
    amp0[e] = 1.0f + fabsf(x[base + idx]) * 0.01f;
    float f;
    if (e == 0)      f = 1.0f + 3.0f * (float)idx * (1.0f / 63.0f);
    else if (e < 3)  f = 4.0f + 4.0f * (float)(idx - 64) * (1.0f / 127.0f);
    else             f = 30.0f + 50.0f * (float)(idx - 192) * (1.0f / 511.0f);
    const float rev = 0.01f * f;               // dt*f revolutions per step
    dc[e] = __builtin_amdgcn_cosf(rev);
    ds[e] = __builtin_amdgcn_sinf(rev);
  }

  float prodT = 1.0f, prodG = 1.0f;            // cumulative band amp gains

#pragma unroll 1
  for (int st = 0; st < 5; ++st) {
    const float Sd = wsum_f(s[0]);
    const float Cd = wsum_f(c[0]);
    const float St = wsum_f(s[1] + s[2]);
    const float Ct = wsum_f(c[1] + c[2]);
    const float sg8 = ((s[3] + s[4]) + (s[5] + s[6])) + ((s[7] + s[8]) + (s[9] + s[10]));
    const float cg8 = ((c[3] + c[4]) + (c[5] + c[6])) + ((c[7] + c[8]) + (c[9] + c[10]));
    const float Sg = wsum_f(sg8);
    const float Cg = wsum_f(cg8);
    // cos(mean phase) per driving band
    const float cpd = Cd * __builtin_amdgcn_rsqf(fmaf(Sd, Sd, Cd * Cd));
    const float cpt = Ct * __builtin_amdgcn_rsqf(fmaf(St, St, Ct * Ct));
    prodT *= fmaf(0.003f, cpd, 1.0f);
    prodG *= fmaf(0.003f, cpt, 1.0f);
    // eps = dt*K*(Sm*c - Cm*s); fold dt*K/n into the sums
    const float sd2 = Sd * (0.02f / 64.0f),  cd2 = Cd * (0.02f / 64.0f);
    const float st2 = St * (0.02f / 128.0f), ct2 = Ct * (0.02f / 128.0f);
    const float sg2 = Sg * (0.02f / 512.0f), cg2 = Cg * (0.02f / 512.0f);
#pragma unroll
    for (int e = 0; e < 11; ++e) {
      const float Sm = (e == 0) ? sd2 : (e < 3) ? st2 : sg2;
      const float Cm = (e == 0) ? cd2 : (e < 3) ? ct2 : cg2;
      const float eps = fmaf(-Cm, s[e], Sm * c[e]);        // radians, |eps|<=0.04
      const float e2 = eps * eps;
      const float ce = fmaf(-0.5f, e2, 1.0f);              // cos(eps); sin(eps)~=eps
      const float cosd = fmaf(-ds[e], eps, dc[e] * ce);    // cos(A+eps)
      const float sind = fmaf(dc[e], eps, ds[e] * ce);     // sin(A+eps)
      const float sn = fmaf(c[e], sind, s[e] * cosd);
      const float cn = fmaf(-s[e], sind, c[e] * cosd);
      s[e] = sn; c[e] = cn;
    }
  }

  // rates
  float raw[11];
  unsigned k[11];
#pragma unroll
  for (int e = 0; e < 11; ++e) {
    const float a = (e == 0) ? amp0[e] : amp0[e] * ((e < 3) ? prodT : prodG);
    const float h = 0.5f * a;
    raw[e] = fmaf(h, c[e], h);                 // amp*0.5*(1+cos)
    k[e] = (unsigned)(raw[e] * 8192.0f);       // 14-bit monotone key (raw < 2)
  }

  // bucket search: minimal B with count(k <= B) >= 633
  unsigned pre = 0;
#pragma unroll 1
  for (int bit = 13; bit >= 0; --bit) {
    const unsigned u = pre | ((1u << bit) - 1u);
    int cnt = 0;
#pragma unroll
    for (int e = 0; e < 11; ++e) cnt += (k[e] <= u) ? 1 : 0;
    cnt = wsum_i(cnt);
    if (cnt < 633) pre |= (1u << bit);
  }
  const unsigned B = pre;

  int clt = 0, cle = 0;
#pragma unroll
  for (int e = 0; e < 11; ++e) { clt += (k[e] < B) ? 1 : 0; cle += (k[e] <= B) ? 1 : 0; }
  clt = wsum_i(clt);
  cle = wsum_i(cle);
  const int r632 = 632 - clt;
  const int r633 = 633 - clt;
  const bool have633 = (cle >= 634);

  const float INF = __int_as_float(0x7F800000);
  float av[11];
#pragma unroll
  for (int e = 0; e < 11; ++e) av[e] = (k[e] == B) ? raw[e] : INF;

  float S632 = 0.0f, S633 = 0.0f;
  int idx = 0;
#pragma unroll 1
  for (int it = 0; it < 705; ++it) {
    float m = av[0];
#pragma unroll
    for (int e = 1; e < 11; ++e) m = fminf(m, av[e]);
    const float mn = wmin_f(m);
    int cm = 0;
#pragma unroll
    for (int e = 0; e < 11; ++e) cm += (av[e] == mn) ? 1 : 0;
    const int cmn = wsum_i(cm);
    if (idx <= r632 && r632 < idx + cmn) S632 = mn;
    if (have633) {
      if (idx <= r633 && r633 < idx + cmn) { S633 = mn; break; }
    } else if (idx + cmn > r632) {
      break;
    }
#pragma unroll
    for (int e = 0; e < 11; ++e) av[e] = (av[e] == mn) ? INF : av[e];
    idx += cmn;
  }
  if (!have633) {
    float bv = INF;
#pragma unroll
    for (int e = 0; e < 11; ++e) bv = (k[e] > B) ? fminf(bv, raw[e]) : bv;
    S633 = wmin_f(bv);
  }

  const float qv = 0.9f * 703.0f;
  const float thr = S632 * (633.0f - qv) + S633 * (qv - 632.0f);

#pragma unroll
  for (int e = 0; e < 11; ++e) {
    const float r = raw[e];
    const float t = __expf((thr - r) * 10.0f);
    const float sg = __builtin_amdgcn_rcpf(1.0f + t);
    rateb[base + e * 64 + lane] = f2bf(r * sg);
  }
}

// ---------------- bf16 MFMA GEMM: out = rate @ W^T + b ----------------
#define BM 128
#define BN 128
#define BK 64

__device__ __forceinline__ void gload16(const unsigned short* g, unsigned short* l) {
  __builtin_amdgcn_global_load_lds((const __attribute__((address_space(1))) void*)g,
                                   (__attribute__((address_space(3))) void*)l,
                                   16, 0, 0);
}

__global__ __launch_bounds__(256) void gemm_kernel(const unsigned short* __restrict__ A,
                                                   const unsigned short* __restrict__ Bw,
                                                   const float* __restrict__ bias,
                                                   float* __restrict__ C) {
  __shared__ unsigned short lA[BM * BK];
  __shared__ unsigned short lB[BN * BK];
  const int tid  = threadIdx.x;
  const int wave = tid >> 6;
  const int lane = tid & 63;

  // XCD-bijective swizzle (nwg=4096, 8 XCDs, 512 per XCD)
  const int bid = blockIdx.x;
  const int swz = (bid & 7) * 512 + (bid >> 3);
  const int bm = swz >> 3;     // 0..511
  const int bn = swz & 7;      // 0..7

  const int wr = wave >> 1;    // 0..1
  const int wc = wave & 1;     // 0..1

  f32x4 acc[4][4];
#pragma unroll
  for (int i = 0; i < 4; ++i)
#pragma unroll
    for (int j = 0; j < 4; ++j) acc[i][j] = (f32x4){0.f, 0.f, 0.f, 0.f};

  const int lrow = lane >> 3;         // 0..7 within 8-row chunk
  const int lk   = (lane & 7) * 8;    // k elem offset within BK

  for (int kt = 0; kt < KDIM / BK; ++kt) {
    const int k0 = kt * BK;
#pragma unroll
    for (int i = 0; i < 4; ++i) {
      const int c = wave * 4 + i;                    // chunk 0..15, wave-uniform
      const size_t garow = (size_t)(bm * BM + c * 8 + lrow);
      gload16(A + garow * KDIM + k0 + lk, lA + c * 512);
      const size_t gbrow = (size_t)(bn * BN + c * 8 + lrow);
      gload16(Bw + gbrow * KDIM + k0 + lk, lB + c * 512);
    }
    __syncthreads();
#pragma unroll
    for (int ks = 0; ks < 2; ++ks) {
      bf16x8 av[4], bv[4];
#pragma unroll
      for (int m = 0; m < 4; ++m)
        av[m] = *(const bf16x8*)&lA[(wr * 64 + m * 16 + (lane & 15)) * BK + ks * 32 + (lane >> 4) * 8];
#pragma unroll
      for (int n = 0; n < 4; ++n)
        bv[n] = *(const bf16x8*)&lB[(wc * 64 + n * 16 + (lane & 15)) * BK + ks * 32 + (lane >> 4) * 8];
#pragma unroll
      for (int m = 0; m < 4; ++m)
#pragma unroll
        for (int n = 0; n < 4; ++n)
          acc[m][n] = __builtin_amdgcn_mfma_f32_16x16x32_bf16(av[m], bv[n], acc[m][n], 0, 0, 0);
    }
    __syncthreads();
  }

  // epilogue: D[row = (lane>>4)*4 + r][col = lane&15] per 16x16 frag
  const int crow0 = bm * BM + wr * 64;
  const int ccol0 = bn * BN + wc * 64;
  const int rql = (lane >> 4) * 4;
  const int cl  = lane & 15;
#pragma unroll
  for (int n = 0; n < 4; ++n) {
    const int col = ccol0 + n * 16 + cl;
    if (col < NCLS) {
      const float bb = bias[col];
#pragma unroll
      for (int m = 0; m < 4; ++m) {
#pragma unroll
        for (int r = 0; r < 4; ++r) {
          const int row = crow0 + m * 16 + rql + r;
          C[(size_t)row * NCLS + col] = acc[m][n][r] + bb;
        }
      }
    }
  }
}

extern "C" void kernel_launch(void* const* d_in, const int* in_sizes, int n_in,
                              void* d_out, int out_size, void* d_ws, size_t ws_size,
                              hipStream_t stream) {
  const float* x    = (const float*)d_in[0];
  const float* p0   = (const float*)d_in[1];
  const float* W    = (const float*)d_in[2];
  const float* bias = (const float*)d_in[3];
  float* out = (float*)d_out;

  unsigned short* Wb    = (unsigned short*)d_ws;                       // NPAD*KDIM bf16
  unsigned short* rateb = (unsigned short*)d_ws + (size_t)NPAD * KDIM; // NB*NTOT bf16

  convw_kernel<<<dim3((NPAD * KDIM + 255) / 256), dim3(256), 0, stream>>>(W, Wb);
  sim_kernel<<<dim3(NB / 4), dim3(256), 0, stream>>>(x, p0, rateb);
  gemm_kernel<<<dim3((NB / BM) * (NPAD / BN)), dim3(256), 0, stream>>>(rateb, Wb, bias, out);
}

// Round 4
// 359.866 us; speedup vs baseline: 1.6548x; 1.2304x over previous
//
#include <hip/hip_runtime.h>

#define NB 65536
#define NTOT 704
#define NCLS 1000
#define NPAD 1024
#define KDIM 704

typedef __attribute__((ext_vector_type(8))) short bf16x8;
typedef __attribute__((ext_vector_type(4))) float f32x4;
typedef __attribute__((ext_vector_type(2))) float f32x2;

#define WB_ELEMS (NPAD * KDIM)
#define LUT_DC_OFF (2u * (WB_ELEMS + 46137344u))          // bytes: after Wb + rateb
#define LUT_DS_OFF (LUT_DC_OFF + NTOT * 4u)

__device__ __forceinline__ f32x2 sp(float x) { return (f32x2){x, x}; }

template <int CTRL>
__device__ __forceinline__ float dpp_shuf(float v) {
  return __int_as_float(__builtin_amdgcn_update_dpp(0, __float_as_int(v), CTRL, 0xF, 0xF, true));
}
__device__ __forceinline__ float swz16(float v) {
  return __int_as_float(__builtin_amdgcn_ds_swizzle(__float_as_int(v), 0x401F)); // xor 16
}
// all-lanes butterfly sum: xor1, xor2, half-mirror, mirror, xor16, xor32
__device__ __forceinline__ float wsum_f(float v) {
  v += dpp_shuf<0xB1>(v);   // quad_perm [1,0,3,2]
  v += dpp_shuf<0x4E>(v);   // quad_perm [2,3,0,1]
  v += dpp_shuf<0x141>(v);  // row_half_mirror
  v += dpp_shuf<0x140>(v);  // row_mirror
  v += swz16(v);
  v += __shfl_xor(v, 32, 64);
  return v;
}
__device__ __forceinline__ float wmax_f(float v) {
  v = fmaxf(v, dpp_shuf<0xB1>(v));
  v = fmaxf(v, dpp_shuf<0x4E>(v));
  v = fmaxf(v, dpp_shuf<0x141>(v));
  v = fmaxf(v, dpp_shuf<0x140>(v));
  v = fmaxf(v, swz16(v));
  v = fmaxf(v, __shfl_xor(v, 32, 64));
  return v;
}
__device__ __forceinline__ float wmin_f(float v) {
  v = fminf(v, dpp_shuf<0xB1>(v));
  v = fminf(v, dpp_shuf<0x4E>(v));
  v = fminf(v, dpp_shuf<0x141>(v));
  v = fminf(v, dpp_shuf<0x140>(v));
  v = fminf(v, swz16(v));
  v = fminf(v, __shfl_xor(v, 32, 64));
  return v;
}

__device__ __forceinline__ unsigned short f2bf(float v) {
  unsigned u = __float_as_uint(v);
  u = (u + 0x7FFFu + ((u >> 16) & 1u)) >> 16;   // RNE
  return (unsigned short)u;
}

// ---------------- W -> bf16 (padded) + rotor LUT ----------------
__global__ __launch_bounds__(256) void convw_kernel(const float* __restrict__ W,
                                                    unsigned short* __restrict__ Wb,
                                                    float* __restrict__ dcL,
                                                    float* __restrict__ dsL) {
  int i = blockIdx.x * 256 + threadIdx.x;
  if (i < NTOT) {
    float f;
    if (i < 64)       f = 1.0f + 3.0f * (float)i * (1.0f / 63.0f);
    else if (i < 192) f = 4.0f + 4.0f * (float)(i - 64) * (1.0f / 127.0f);
    else              f = 30.0f + 50.0f * (float)(i - 192) * (1.0f / 511.0f);
    const float rev = 0.01f * f;                 // dt*f revolutions per step
    dcL[i] = __builtin_amdgcn_cosf(rev);
    dsL[i] = __builtin_amdgcn_sinf(rev);
  }
  if (i >= NPAD * KDIM) return;
  int n = i / KDIM;
  float v = (n < NCLS) ? W[i] : 0.0f;
  Wb[i] = f2bf(v);
}

// ---------------- oscillator sim + quantile gate -> rate(bf16) ----------------
__global__ __launch_bounds__(256) void sim_kernel(const float* __restrict__ x,
                                                  const float* __restrict__ p0,
                                                  const float* __restrict__ dcL,
                                                  const float* __restrict__ dsL,
                                                  unsigned short* __restrict__ rateb) {
  const int wave = threadIdx.x >> 6;
  const int lane = threadIdx.x & 63;
  const int sample = blockIdx.x * 4 + wave;
  const size_t base = (size_t)sample * NTOT;

  // delta: scalar element (e=0); theta pair (1,2); gamma pairs (3,4)..(9,10)
  float sD, cD, ampD, dcD, dsD;
  f32x2 sPp[5], cPp[5], dc2[5], ds2[5], amp2[5];
  {
    const float p = p0[base + lane];
    sD = __builtin_amdgcn_sinf(p);
    cD = __builtin_amdgcn_cosf(p);
    ampD = fmaf(fabsf(x[base + lane]), 0.01f, 1.0f);
    dcD = dcL[lane]; dsD = dsL[lane];
  }
#pragma unroll
  for (int pr = 0; pr < 5; ++pr) {
    const int i0 = (1 + 2 * pr) * 64 + lane;
    const int i1 = i0 + 64;
    const float pa = p0[base + i0], pb = p0[base + i1];
    sPp[pr] = (f32x2){__builtin_amdgcn_sinf(pa), __builtin_amdgcn_sinf(pb)};
    cPp[pr] = (f32x2){__builtin_amdgcn_cosf(pa), __builtin_amdgcn_cosf(pb)};
    amp2[pr] = (f32x2){fmaf(fabsf(x[base + i0]), 0.01f, 1.0f),
                       fmaf(fabsf(x[base + i1]), 0.01f, 1.0f)};
    dc2[pr] = (f32x2){dcL[i0], dcL[i1]};
    ds2[pr] = (f32x2){dsL[i0], dsL[i1]};
  }

  float prodT = 1.0f, prodG = 1.0f;

#pragma unroll
  for (int st = 0; st < 5; ++st) {
    const float Sd = wsum_f(sD);
    const float Cd = wsum_f(cD);
    const float St = wsum_f(sPp[0].x + sPp[0].y);
    const float Ct = wsum_f(cPp[0].x + cPp[0].y);
    const f32x2 gs = (sPp[1] + sPp[2]) + (sPp[3] + sPp[4]);
    const f32x2 gc = (cPp[1] + cPp[2]) + (cPp[3] + cPp[4]);
    const float Sg = wsum_f(gs.x + gs.y);
    const float Cg = wsum_f(gc.x + gc.y);
    const float cpd = Cd * __builtin_amdgcn_rsqf(fmaf(Sd, Sd, Cd * Cd));
    const float cpt = Ct * __builtin_amdgcn_rsqf(fmaf(St, St, Ct * Ct));
    prodT *= fmaf(0.003f, cpd, 1.0f);
    prodG *= fmaf(0.003f, cpt, 1.0f);
    const float sdm = Sd * (0.02f / 64.0f),  cdm = Cd * (0.02f / 64.0f);
    const float stm = St * (0.02f / 128.0f), ctm = Ct * (0.02f / 128.0f);
    const float sgm = Sg * (0.02f / 512.0f), cgm = Cg * (0.02f / 512.0f);
    // delta (scalar)
    {
      const float eps = fmaf(-cdm, sD, sdm * cD);
      const float e2 = eps * eps;
      const float ce = fmaf(-0.5f, e2, 1.0f);
      const float cd_ = fmaf(-dsD, eps, dcD * ce);
      const float sd_ = fmaf(dcD, eps, dsD * ce);
      const float sn = fmaf(cD, sd_, sD * cd_);
      const float cn = fmaf(-sD, sd_, cD * cd_);
      sD = sn; cD = cn;
    }
    // pairs (packed f32)
#pragma unroll
    for (int pr = 0; pr < 5; ++pr) {
      const f32x2 Sm = sp(pr == 0 ? stm : sgm);
      const f32x2 Cm = sp(pr == 0 ? ctm : cgm);
      const f32x2 s2 = sPp[pr], c2 = cPp[pr];
      const f32x2 eps = Sm * c2 - Cm * s2;
      const f32x2 e2 = eps * eps;
      const f32x2 ce = sp(1.0f) - sp(0.5f) * e2;
      const f32x2 cosd = dc2[pr] * ce - ds2[pr] * eps;
      const f32x2 sind = ds2[pr] * ce + dc2[pr] * eps;
      sPp[pr] = s2 * cosd + c2 * sind;
      cPp[pr] = c2 * cosd - s2 * sind;
    }
  }

  // rates + 14-bit keys
  float raw[11];
  unsigned kk[11];
  {
    const float h = 0.5f * ampD;
    raw[0] = fmaf(h, cD, h);
  }
  const float hT = 0.5f * prodT, hG = 0.5f * prodG;
#pragma unroll
  for (int pr = 0; pr < 5; ++pr) {
    const f32x2 h2 = amp2[pr] * sp(pr == 0 ? hT : hG);
    const f32x2 r2 = h2 * cPp[pr] + h2;
    raw[1 + 2 * pr] = r2.x;
    raw[2 + 2 * pr] = r2.y;
  }
#pragma unroll
  for (int e = 0; e < 11; ++e) kk[e] = (unsigned)(raw[e] * 8192.0f);

  // minimal B with count(k <= B) >= 633 — ballot+popcount (SALU-heavy)
  unsigned pre = 0;
#pragma unroll
  for (int bit = 13; bit >= 0; --bit) {
    const unsigned u = pre | ((1u << bit) - 1u);
    int cnt = 0;
#pragma unroll
    for (int e = 0; e < 11; ++e) cnt += (int)__popcll(__ballot(kk[e] <= u));
    if (cnt < 633) pre |= (1u << bit);
  }

  int clt = 0, ceq = 0;
#pragma unroll
  for (int e = 0; e < 11; ++e) {
    clt += (int)__popcll(__ballot(kk[e] < pre));
    ceq += (int)__popcll(__ballot(kk[e] == pre));
  }

  const float qv = 0.9f * 703.0f;
  float thr;
  if (clt + ceq >= 634) {
    // both order stats inside bucket (width 1/8192): center approx, err <= 1.2e-4
    thr = ((float)pre + 0.5f) * (1.0f / 8192.0f);
  } else {
    // exactly 633 values <= B: S632 = max(k==B), S633 = min(k>B)
    float mx = -1.0f, mn = 3.0e38f;
#pragma unroll
    for (int e = 0; e < 11; ++e) {
      mx = fmaxf(mx, (kk[e] == pre) ? raw[e] : -1.0f);
      mn = fminf(mn, (kk[e] > pre) ? raw[e] : 3.0e38f);
    }
    const float S632 = wmax_f(mx);
    const float S633 = wmin_f(mn);
    thr = S632 * (633.0f - qv) + S633 * (qv - 632.0f);
  }

#pragma unroll
  for (int e = 0; e < 11; ++e) {
    const float r = raw[e];
    const float t = __expf((thr - r) * 10.0f);
    const float sg = __builtin_amdgcn_rcpf(1.0f + t);
    rateb[base + e * 64 + lane] = f2bf(r * sg);
  }
}

// ---------------- bf16 MFMA GEMM: out = rate @ W^T + b ----------------
#define BM 128
#define BN 128
#define BK 64

__device__ __forceinline__ void gload16(const unsigned short* g, unsigned short* l) {
  __builtin_amdgcn_global_load_lds((const __attribute__((address_space(1))) void*)g,
                                   (__attribute__((address_space(3))) void*)l,
                                   16, 0, 0);
}

__global__ __launch_bounds__(256) void gemm_kernel(const unsigned short* __restrict__ A,
                                                   const unsigned short* __restrict__ Bw,
                                                   const float* __restrict__ bias,
                                                   float* __restrict__ C) {
  __shared__ unsigned short lA[BM * BK];
  __shared__ unsigned short lB[BN * BK];
  const int tid  = threadIdx.x;
  const int wave = tid >> 6;
  const int lane = tid & 63;

  // XCD-bijective swizzle (nwg=4096, 8 XCDs, 512 per XCD)
  const int bid = blockIdx.x;
  const int swz = (bid & 7) * 512 + (bid >> 3);
  const int bm = swz >> 3;     // 0..511
  const int bn = swz & 7;      // 0..7

  const int wr = wave >> 1;    // 0..1
  const int wc = wave & 1;     // 0..1

  f32x4 acc[4][4];
#pragma unroll
  for (int i = 0; i < 4; ++i)
#pragma unroll
    for (int j = 0; j < 4; ++j) acc[i][j] = (f32x4){0.f, 0.f, 0.f, 0.f};

  const int lrow = lane >> 3;         // 0..7 within 8-row chunk
  const int lk   = (lane & 7) * 8;    // k elem offset within BK

  for (int kt = 0; kt < KDIM / BK; ++kt) {
    const int k0 = kt * BK;
#pragma unroll
    for (int i = 0; i < 4; ++i) {
      const int c = wave * 4 + i;                    // chunk 0..15, wave-uniform
      const size_t garow = (size_t)(bm * BM + c * 8 + lrow);
      gload16(A + garow * KDIM + k0 + lk, lA + c * 512);
      const size_t gbrow = (size_t)(bn * BN + c * 8 + lrow);
      gload16(Bw + gbrow * KDIM + k0 + lk, lB + c * 512);
    }
    __syncthreads();
#pragma unroll
    for (int ks = 0; ks < 2; ++ks) {
      bf16x8 av[4], bv[4];
#pragma unroll
      for (int m = 0; m < 4; ++m)
        av[m] = *(const bf16x8*)&lA[(wr * 64 + m * 16 + (lane & 15)) * BK + ks * 32 + (lane >> 4) * 8];
#pragma unroll
      for (int n = 0; n < 4; ++n)
        bv[n] = *(const bf16x8*)&lB[(wc * 64 + n * 16 + (lane & 15)) * BK + ks * 32 + (lane >> 4) * 8];
#pragma unroll
      for (int m = 0; m < 4; ++m)
#pragma unroll
        for (int n = 0; n < 4; ++n)
          acc[m][n] = __builtin_amdgcn_mfma_f32_16x16x32_bf16(av[m], bv[n], acc[m][n], 0, 0, 0);
    }
    __syncthreads();
  }

  const int crow0 = bm * BM + wr * 64;
  const int ccol0 = bn * BN + wc * 64;
  const int rql = (lane >> 4) * 4;
  const int cl  = lane & 15;
#pragma unroll
  for (int n = 0; n < 4; ++n) {
    const int col = ccol0 + n * 16 + cl;
    if (col < NCLS) {
      const float bb = bias[col];
#pragma unroll
      for (int m = 0; m < 4; ++m) {
#pragma unroll
        for (int r = 0; r < 4; ++r) {
          const int row = crow0 + m * 16 + rql + r;
          C[(size_t)row * NCLS + col] = acc[m][n][r] + bb;
        }
      }
    }
  }
}

extern "C" void kernel_launch(void* const* d_in, const int* in_sizes, int n_in,
                              void* d_out, int out_size, void* d_ws, size_t ws_size,
                              hipStream_t stream) {
  const float* x    = (const float*)d_in[0];
  const float* p0   = (const float*)d_in[1];
  const float* W    = (const float*)d_in[2];
  const float* bias = (const float*)d_in[3];
  float* out = (float*)d_out;

  unsigned short* Wb    = (unsigned short*)d_ws;
  unsigned short* rateb = (unsigned short*)d_ws + WB_ELEMS;
  float* dcL = (float*)((char*)d_ws + LUT_DC_OFF);
  float* dsL = (float*)((char*)d_ws + LUT_DS_OFF);

  convw_kernel<<<dim3((NPAD * KDIM + 255) / 256), dim3(256), 0, stream>>>(W, Wb, dcL, dsL);
  sim_kernel<<<dim3(NB / 4), dim3(256), 0, stream>>>(x, p0, dcL, dsL, rateb);
  gemm_kernel<<<dim3((NB / BM) * (NPAD / BN)), dim3(256), 0, stream>>>(rateb, Wb, bias, out);
}